// Round 1
// baseline (3025.320 us; speedup 1.0000x reference)
//
#include <hip/hip_runtime.h>
#include <math.h>

#define D_MODEL   768
#define N_LAYER   4
#define D_STATE   128
#define D_CONV    4
#define HEADDIM   64
#define CHUNK     64
#define NCHUNK    32      // SEQLEN / CHUNK
#define VOCAB     50288
#define D_INNER   1536
#define NHEADS    24
#define CONV_DIM  1792    // D_INNER + 2*D_STATE
#define D_IN_PROJ 3352    // 2*D_INNER + 2*D_STATE + NHEADS
#define SEQLEN    2048
#define EPS       1e-5f

typedef float f32x4 __attribute__((ext_vector_type(4)));
typedef short bf16x8 __attribute__((ext_vector_type(8)));
typedef short bf16x4 __attribute__((ext_vector_type(4)));

// ---------------- block-wide reduction (256 threads = 4 waves) ----------------
__device__ __forceinline__ float blk_reduce_sum(float v, float* red) {
  #pragma unroll
  for (int off = 32; off > 0; off >>= 1) v += __shfl_down(v, off, 64);
  if ((threadIdx.x & 63) == 0) red[threadIdx.x >> 6] = v;
  __syncthreads();
  float s = red[0] + red[1] + red[2] + red[3];
  __syncthreads();
  return s;
}

__device__ __forceinline__ float silu_f(float x) {
  return x / (1.f + expf(-x));
}

// RNE fp32 -> bf16 (top 16 bits)
__device__ __forceinline__ unsigned short bf16_rne(float x) {
  unsigned int u = __builtin_bit_cast(unsigned int, x);
  u += 0x7FFFu + ((u >> 16) & 1u);
  return (unsigned short)(u >> 16);
}

// split fp32 x into hi+lo bf16 pair: x ~= hi + lo, |x-hi-lo| <= 2^-18 |x|
__device__ __forceinline__ void split4(float4 v, bf16x4& h, bf16x4& l) {
  float vv[4] = {v.x, v.y, v.z, v.w};
  #pragma unroll
  for (int i = 0; i < 4; i++) {
    unsigned int u = __builtin_bit_cast(unsigned int, vv[i]);
    unsigned int rh = u + 0x7FFFu + ((u >> 16) & 1u);
    unsigned short hs = (unsigned short)(rh >> 16);
    float hf = __builtin_bit_cast(float, rh & 0xFFFF0000u);
    unsigned short ls = bf16_rne(vv[i] - hf);
    h[i] = (short)hs;
    l[i] = (short)ls;
  }
}

// ---------------- embedding gather ----------------
__global__ void embed_k(const int* __restrict__ ids, const float* __restrict__ emb,
                        float* __restrict__ x) {
  int t = blockIdx.x;
  size_t src = (size_t)ids[t] * D_MODEL;
  for (int i = threadIdx.x; i < D_MODEL; i += 256)
    x[(size_t)t * D_MODEL + i] = emb[src + i];
}

// ---------------- rmsnorm over 768 (pre-layer + final) ----------------
__global__ void rmsnorm768_k(const float* __restrict__ in, const float* __restrict__ w,
                             float* __restrict__ out) {
  __shared__ float red[4];
  int t = blockIdx.x;
  const float* row = in + (size_t)t * D_MODEL;
  int i0 = threadIdx.x, i1 = i0 + 256, i2 = i0 + 512;
  float v0 = row[i0], v1 = row[i1], v2 = row[i2];
  float ss = blk_reduce_sum(v0 * v0 + v1 * v1 + v2 * v2, red);
  float sc = rsqrtf(ss * (1.f / D_MODEL) + EPS);
  float* orow = out + (size_t)t * D_MODEL;
  orow[i0] = v0 * sc * w[i0];
  orow[i1] = v1 * sc * w[i1];
  orow[i2] = v2 * sc * w[i2];
}

// ---------------- gated rmsnorm over 1536: out = rms(y*silu(z)) * w ----------------
__global__ void gated_rmsnorm_k(const float* __restrict__ y, const float* __restrict__ zx,
                                const float* __restrict__ w, float* __restrict__ out) {
  __shared__ float red[4];
  int t = blockIdx.x;
  const float* yr = y + (size_t)t * D_INNER;
  const float* zr = zx + (size_t)t * D_IN_PROJ;   // z = first 1536 of zxbcdt
  float v[6];
  float ss = 0.f;
  #pragma unroll
  for (int i = 0; i < 6; i++) {
    int idx = threadIdx.x + i * 256;
    float val = yr[idx] * silu_f(zr[idx]);
    v[i] = val;
    ss += val * val;
  }
  ss = blk_reduce_sum(ss, red);
  float sc = rsqrtf(ss * (1.f / D_INNER) + EPS);
  float* orow = out + (size_t)t * D_INNER;
  #pragma unroll
  for (int i = 0; i < 6; i++) {
    int idx = threadIdx.x + i * 256;
    orow[idx] = v[i] * sc * w[idx];
  }
}

// ---------------- split-bf16 MFMA NT GEMM ----------------
// C[M,N] = A[M,K] @ B[N,K]^T (+res), fp32 in/out, internally split each
// operand into hi/lo bf16 and run 3 MFMA products (Markidis): error ~2^-17.
// 128x128 tile, BK=32, 256 threads = 4 waves in 2x2, each wave 64x64 via
// 4x4 frags of v_mfma_f32_16x16x32_bf16. M must be /128; N,K arbitrary/32.
#define GBM 128
#define GBN 128
#define GBK 32
#define GROWS 40            // shorts per LDS row (32 data + 8 pad -> 2-way max)
#define GPLANE (128 * GROWS)

__global__ __launch_bounds__(256) void gemm_nt_mfma_k(
    const float* __restrict__ A, const float* __restrict__ B,
    float* __restrict__ C, const float* __restrict__ res,
    int M, int N, int K) {
  __shared__ __align__(16) short lds[4 * GPLANE];   // planes: Ah, Al, Bh, Bl
  int tid = threadIdx.x;
  int bm = blockIdx.y * GBM, bn = blockIdx.x * GBN;
  int wave = tid >> 6, lane = tid & 63;
  int wr = wave >> 1, wc = wave & 1;       // 2x2 wave grid, each 64x64 out
  int lrow = lane & 15, kq = lane >> 4;    // frag row / k-group

  f32x4 acc[4][4] = {};

  for (int k0 = 0; k0 < K; k0 += GBK) {
    // ---- issue global loads (fp32) ----
    float4 ra[4], rb[4];
    #pragma unroll
    for (int r = 0; r < 4; r++) {
      int flat = (r << 8) + tid;       // 0..1023
      int row = flat >> 3;             // 0..127
      int q = flat & 7;                // float4 slot in 32-wide k
      ra[r] = *(const float4*)&A[(size_t)(bm + row) * K + k0 + (q << 2)];
      int brow = bn + row;
      if (brow < N)
        rb[r] = *(const float4*)&B[(size_t)brow * K + k0 + (q << 2)];
      else
        rb[r] = make_float4(0.f, 0.f, 0.f, 0.f);
    }
    __syncthreads();   // previous iteration's frag reads complete
    // ---- convert to hi/lo bf16 and stage to LDS ----
    #pragma unroll
    for (int r = 0; r < 4; r++) {
      int flat = (r << 8) + tid;
      int row = flat >> 3;
      int q = flat & 7;
      int eoff = row * GROWS + (q << 2);
      bf16x4 h4, l4;
      split4(ra[r], h4, l4);
      *(bf16x4*)&lds[0 * GPLANE + eoff] = h4;
      *(bf16x4*)&lds[1 * GPLANE + eoff] = l4;
      split4(rb[r], h4, l4);
      *(bf16x4*)&lds[2 * GPLANE + eoff] = h4;
      *(bf16x4*)&lds[3 * GPLANE + eoff] = l4;
    }
    __syncthreads();
    // ---- fragment loads ----
    bf16x8 ah[4], al[4], bh[4], bl[4];
    #pragma unroll
    for (int m = 0; m < 4; m++) {
      int aoff = (wr * 64 + m * 16 + lrow) * GROWS + kq * 8;
      ah[m] = *(const bf16x8*)&lds[0 * GPLANE + aoff];
      al[m] = *(const bf16x8*)&lds[1 * GPLANE + aoff];
      int boff = (wc * 64 + m * 16 + lrow) * GROWS + kq * 8;
      bh[m] = *(const bf16x8*)&lds[2 * GPLANE + boff];
      bl[m] = *(const bf16x8*)&lds[3 * GPLANE + boff];
    }
    // ---- 48 MFMAs: hi*hi + hi*lo + lo*hi ----
    #pragma unroll
    for (int m = 0; m < 4; m++)
      #pragma unroll
      for (int n = 0; n < 4; n++) {
        acc[m][n] = __builtin_amdgcn_mfma_f32_16x16x32_bf16(ah[m], bh[n], acc[m][n], 0, 0, 0);
        acc[m][n] = __builtin_amdgcn_mfma_f32_16x16x32_bf16(ah[m], bl[n], acc[m][n], 0, 0, 0);
        acc[m][n] = __builtin_amdgcn_mfma_f32_16x16x32_bf16(al[m], bh[n], acc[m][n], 0, 0, 0);
      }
  }

  // ---- C write: col = lane&15, row = (lane>>4)*4 + reg  (m89/m91 layout) ----
  #pragma unroll
  for (int m = 0; m < 4; m++) {
    int rbase = bm + wr * 64 + m * 16 + kq * 4;
    #pragma unroll
    for (int n = 0; n < 4; n++) {
      int col = bn + wc * 64 + n * 16 + lrow;
      if (col < N) {
        #pragma unroll
        for (int j = 0; j < 4; j++) {
          size_t ci = (size_t)(rbase + j) * N + col;
          float v = acc[m][n][j];
          if (res) v += res[ci];
          C[ci] = v;
        }
      }
    }
  }
}

// ---------------- depthwise causal conv4 + silu on xBC; softplus dt ----------------
__global__ void conv_dt_k(const float* __restrict__ zx, const float* __restrict__ cw,
                          const float* __restrict__ cb, const float* __restrict__ dtb,
                          float* __restrict__ xbc, float* __restrict__ dtbuf) {
  int idx = blockIdx.x * 256 + threadIdx.x;     // over SEQLEN*CONV_DIM
  int t = idx / CONV_DIM, ch = idx - t * CONV_DIM;
  float acc = cb[ch];
  #pragma unroll
  for (int k = 0; k < 4; k++) {
    int tt = t - 3 + k;
    if (tt >= 0) acc += cw[ch * 4 + k] * zx[(size_t)tt * D_IN_PROJ + D_INNER + ch];
  }
  xbc[(size_t)t * CONV_DIM + ch] = silu_f(acc);
  if (ch < NHEADS) {
    float raw = zx[(size_t)t * D_IN_PROJ + (D_INNER + CONV_DIM) + ch] + dtb[ch];
    dtbuf[t * NHEADS + ch] = (raw > 20.f) ? raw : log1pf(expf(raw));
  }
}

// ---------------- SSD phase 1: per (chunk, head): Y_diag + chunk states + Acum ----------------
__global__ __launch_bounds__(256) void ssd_phase1_k(
    const float* __restrict__ xbc, const float* __restrict__ dtbuf,
    const float* __restrict__ A_log, float* __restrict__ ybuf,
    float* __restrict__ states, float* __restrict__ acum_g) {
  __shared__ float Bs[64][129];
  __shared__ float Cs[64][129];
  __shared__ float Xs[64][65];
  __shared__ float Gs[64][65];
  __shared__ float ac[64], dts[64], decay[64];
  int c = blockIdx.x, h = blockIdx.y, tid = threadIdx.x;

  if (tid < 64) dts[tid] = dtbuf[(c * 64 + tid) * NHEADS + h];
  __syncthreads();
  if (tid == 0) {
    float Ah = -expf(A_log[h]);
    float s = 0.f;
    for (int l = 0; l < 64; l++) { s += Ah * dts[l]; ac[l] = s; }
  }
  __syncthreads();
  if (tid < 64) {
    decay[tid] = expf(ac[63] - ac[tid]);
    acum_g[(h * NCHUNK + c) * 64 + tid] = ac[tid];
  }
  for (int idx = tid; idx < 64 * 128; idx += 256) {
    int l = idx >> 7, n = idx & 127;
    const float* row = xbc + (size_t)(c * 64 + l) * CONV_DIM;
    Bs[l][n] = row[D_INNER + n];
    Cs[l][n] = row[D_INNER + D_STATE + n];
  }
  for (int idx = tid; idx < 64 * 64; idx += 256) {
    int l = idx >> 6, p = idx & 63;
    Xs[l][p] = xbc[(size_t)(c * 64 + l) * CONV_DIM + h * 64 + p] * dts[l];
  }
  __syncthreads();
  // states[p][n] = sum_l x[l][p]*decay[l]*B[l][n]
  for (int idx = tid; idx < 64 * 128; idx += 256) {
    int p = idx >> 7, n = idx & 127;
    float s = 0.f;
    for (int l = 0; l < 64; l++) s += Xs[l][p] * decay[l] * Bs[l][n];
    states[((size_t)(h * NCHUNK + c) * 64 + p) * 128 + n] = s;
  }
  // G[i][j] = (C_i . B_j) * exp(ac_i - ac_j), j<=i
  for (int idx = tid; idx < 64 * 64; idx += 256) {
    int i = idx >> 6, j = idx & 63;
    float g = 0.f;
    if (j <= i) {
      for (int n = 0; n < 128; n++) g += Cs[i][n] * Bs[j][n];
      g *= expf(ac[i] - ac[j]);
    }
    Gs[i][j] = g;
  }
  __syncthreads();
  // Y_diag[i][p] = sum_{j<=i} G[i][j]*X[j][p]
  for (int idx = tid; idx < 64 * 64; idx += 256) {
    int i = idx >> 6, p = idx & 63;
    float yv = 0.f;
    for (int j = 0; j <= i; j++) yv += Gs[i][j] * Xs[j][p];
    ybuf[(size_t)(c * 64 + i) * D_INNER + h * 64 + p] = yv;
  }
}

// ---------------- SSD phase 2: sequential inter-chunk state scan per head ----------------
__global__ void ssd_scan_k(const float* __restrict__ states, const float* __restrict__ acum_g,
                           float* __restrict__ sprefix) {
  int h = blockIdx.x, tid = threadIdx.x;
  float S[32];
  #pragma unroll
  for (int i = 0; i < 32; i++) S[i] = 0.f;
  for (int c = 0; c < NCHUNK; c++) {
    size_t base = (size_t)(h * NCHUNK + c) * 8192;
    float d = expf(acum_g[(h * NCHUNK + c) * 64 + 63]);
    #pragma unroll
    for (int i = 0; i < 32; i++) {
      size_t off = base + tid + i * 256;
      sprefix[off] = S[i];
      S[i] = d * S[i] + states[off];
    }
  }
}

// ---------------- SSD phase 3: Y += exp(Acum)*C.Sprefix + x*D ----------------
__global__ __launch_bounds__(256) void ssd_phase3_k(
    const float* __restrict__ xbc, const float* __restrict__ sprefix,
    const float* __restrict__ acum_g, const float* __restrict__ Dv,
    float* __restrict__ ybuf) {
  __shared__ float Sp[64][129];
  __shared__ float Cs[64][129];
  __shared__ float ac[64];
  int c = blockIdx.x, h = blockIdx.y, tid = threadIdx.x;
  if (tid < 64) ac[tid] = acum_g[(h * NCHUNK + c) * 64 + tid];
  for (int idx = tid; idx < 64 * 128; idx += 256) {
    int p = idx >> 7, n = idx & 127;
    Sp[p][n] = sprefix[((size_t)(h * NCHUNK + c) * 64 + p) * 128 + n];
    Cs[p][n] = xbc[(size_t)(c * 64 + p) * CONV_DIM + D_INNER + D_STATE + n];
  }
  __syncthreads();
  float Dh = Dv[h];
  for (int idx = tid; idx < 64 * 64; idx += 256) {
    int l = idx >> 6, p = idx & 63;
    float s = 0.f;
    for (int n = 0; n < 128; n++) s += Cs[l][n] * Sp[p][n];
    size_t yi = (size_t)(c * 64 + l) * D_INNER + h * 64 + p;
    float xv = xbc[(size_t)(c * 64 + l) * CONV_DIM + h * 64 + p];
    ybuf[yi] += expf(ac[l]) * s + xv * Dh;
  }
}

// ---------------- host launch ----------------
extern "C" void kernel_launch(void* const* d_in, const int* in_sizes, int n_in,
                              void* d_out, int out_size, void* d_ws, size_t ws_size,
                              hipStream_t stream) {
  const int*   ids  = (const int*)d_in[0];
  const float* emb  = (const float*)d_in[1];
  const float* ipw  = (const float*)d_in[2];   // (4, 3352, 768)
  const float* cw   = (const float*)d_in[3];   // (4, 1792, 4)
  const float* cb   = (const float*)d_in[4];   // (4, 1792)
  const float* dtb  = (const float*)d_in[5];   // (4, 24)
  const float* alog = (const float*)d_in[6];   // (4, 24)
  const float* Dv   = (const float*)d_in[7];   // (4, 24)
  const float* mnw  = (const float*)d_in[8];   // (4, 1536)
  const float* opw  = (const float*)d_in[9];   // (4, 768, 1536)
  const float* lnw  = (const float*)d_in[10];  // (4, 768)
  const float* nfw  = (const float*)d_in[11];  // (768,)
  float* out = (float*)d_out;

  // Scratch layout. Small persistent buffers (x, u) always in d_ws (12.6 MB).
  // Big per-layer transients (105.4 MB) go in d_ws if it fits, else in d_out
  // (412 MB; fully dead before the final vocab GEMM writes it).
  const size_t SMALL_F = 2ull * SEQLEN * D_MODEL;
  const size_t BIG_F = (size_t)SEQLEN * D_IN_PROJ + (size_t)SEQLEN * CONV_DIM +
                       (size_t)SEQLEN * NHEADS + (size_t)SEQLEN * D_INNER +
                       2ull * NHEADS * NCHUNK * CHUNK * D_STATE +
                       (size_t)NHEADS * NCHUNK * CHUNK;
  float* x = (float*)d_ws;
  float* u = x + (size_t)SEQLEN * D_MODEL;
  float* big = (ws_size >= (SMALL_F + BIG_F) * sizeof(float))
                   ? (u + (size_t)SEQLEN * D_MODEL)
                   : (float*)d_out;
  float* zx      = big;
  float* xbc     = zx + (size_t)SEQLEN * D_IN_PROJ;
  float* dtbuf   = xbc + (size_t)SEQLEN * CONV_DIM;
  float* ybuf    = dtbuf + (size_t)SEQLEN * NHEADS;
  float* states  = ybuf + (size_t)SEQLEN * D_INNER;
  float* sprefix = states + (size_t)NHEADS * NCHUNK * CHUNK * D_STATE;
  float* acum    = sprefix + (size_t)NHEADS * NCHUNK * CHUNK * D_STATE;

  embed_k<<<SEQLEN, 256, 0, stream>>>(ids, emb, x);

  for (int i = 0; i < N_LAYER; i++) {
    rmsnorm768_k<<<SEQLEN, 256, 0, stream>>>(x, lnw + i * D_MODEL, u);
    gemm_nt_mfma_k<<<dim3((D_IN_PROJ + GBN - 1) / GBN, SEQLEN / GBM), 256, 0, stream>>>(
        u, ipw + (size_t)i * D_IN_PROJ * D_MODEL, zx, nullptr, SEQLEN, D_IN_PROJ, D_MODEL);
    conv_dt_k<<<(SEQLEN * CONV_DIM) / 256, 256, 0, stream>>>(
        zx, cw + (size_t)i * CONV_DIM * D_CONV, cb + (size_t)i * CONV_DIM,
        dtb + i * NHEADS, xbc, dtbuf);
    ssd_phase1_k<<<dim3(NCHUNK, NHEADS), 256, 0, stream>>>(
        xbc, dtbuf, alog + i * NHEADS, ybuf, states, acum);
    ssd_scan_k<<<NHEADS, 256, 0, stream>>>(states, acum, sprefix);
    ssd_phase3_k<<<dim3(NCHUNK, NHEADS), 256, 0, stream>>>(
        xbc, sprefix, acum, Dv + i * NHEADS, ybuf);
    gated_rmsnorm_k<<<SEQLEN, 256, 0, stream>>>(ybuf, zx, mnw + i * D_INNER, xbc);
    gemm_nt_mfma_k<<<dim3(D_MODEL / GBN, SEQLEN / GBM), 256, 0, stream>>>(
        xbc, opw + (size_t)i * D_MODEL * D_INNER, x, x, SEQLEN, D_MODEL, D_INNER);
  }

  rmsnorm768_k<<<SEQLEN, 256, 0, stream>>>(x, nfw, u);
  gemm_nt_mfma_k<<<dim3((VOCAB + GBN - 1) / GBN, SEQLEN / GBM), 256, 0, stream>>>(
      u, emb, out, nullptr, SEQLEN, VOCAB, D_MODEL);
}

// Round 2
// 2936.030 us; speedup vs baseline: 1.0304x; 1.0304x over previous
//
#include <hip/hip_runtime.h>
#include <math.h>

#define D_MODEL   768
#define N_LAYER   4
#define D_STATE   128
#define D_CONV    4
#define HEADDIM   64
#define CHUNK     64
#define NCHUNK    32      // SEQLEN / CHUNK
#define VOCAB     50288
#define D_INNER   1536
#define NHEADS    24
#define CONV_DIM  1792    // D_INNER + 2*D_STATE
#define D_IN_PROJ 3352    // 2*D_INNER + 2*D_STATE + NHEADS
#define SEQLEN    2048
#define EPS       1e-5f

typedef float f32x4 __attribute__((ext_vector_type(4)));
typedef short bf16x8 __attribute__((ext_vector_type(8)));
typedef short bf16x4 __attribute__((ext_vector_type(4)));

// ---------------- block-wide reduction (256 threads = 4 waves) ----------------
__device__ __forceinline__ float blk_reduce_sum(float v, float* red) {
  #pragma unroll
  for (int off = 32; off > 0; off >>= 1) v += __shfl_down(v, off, 64);
  if ((threadIdx.x & 63) == 0) red[threadIdx.x >> 6] = v;
  __syncthreads();
  float s = red[0] + red[1] + red[2] + red[3];
  __syncthreads();
  return s;
}

__device__ __forceinline__ float silu_f(float x) {
  return x / (1.f + expf(-x));
}

// RNE fp32 -> bf16 (top 16 bits)
__device__ __forceinline__ unsigned short bf16_rne(float x) {
  unsigned int u = __builtin_bit_cast(unsigned int, x);
  u += 0x7FFFu + ((u >> 16) & 1u);
  return (unsigned short)(u >> 16);
}

// split fp32 x into hi+lo bf16 pair: x ~= hi + lo, |x-hi-lo| <= 2^-18 |x|
__device__ __forceinline__ void split1(float x, short& h, short& l) {
  unsigned int u = __builtin_bit_cast(unsigned int, x);
  unsigned int rh = u + 0x7FFFu + ((u >> 16) & 1u);
  h = (short)(unsigned short)(rh >> 16);
  float hf = __builtin_bit_cast(float, rh & 0xFFFF0000u);
  l = (short)bf16_rne(x - hf);
}

__device__ __forceinline__ void split4(float4 v, bf16x4& h, bf16x4& l) {
  float vv[4] = {v.x, v.y, v.z, v.w};
  #pragma unroll
  for (int i = 0; i < 4; i++) {
    short hs, ls;
    split1(vv[i], hs, ls);
    h[i] = hs;
    l[i] = ls;
  }
}

// ---------------- bulk fp32 -> (hi,lo) bf16 splitter ----------------
__global__ void split_k(const float* __restrict__ src, short* __restrict__ h,
                        short* __restrict__ l, long n4) {
  long i = (long)blockIdx.x * 256 + threadIdx.x;
  long stride = (long)gridDim.x * 256;
  for (; i < n4; i += stride) {
    float4 v = ((const float4*)src)[i];
    bf16x4 hh, ll;
    split4(v, hh, ll);
    ((bf16x4*)h)[i] = hh;
    ((bf16x4*)l)[i] = ll;
  }
}

// ---------------- embedding gather ----------------
__global__ void embed_k(const int* __restrict__ ids, const float* __restrict__ emb,
                        float* __restrict__ x) {
  int t = blockIdx.x;
  size_t src = (size_t)ids[t] * D_MODEL;
  for (int i = threadIdx.x; i < D_MODEL; i += 256)
    x[(size_t)t * D_MODEL + i] = emb[src + i];
}

// ---------------- rmsnorm over 768, optional fused bf16 split output ----------------
__global__ void rmsnorm768_k(const float* __restrict__ in, const float* __restrict__ w,
                             float* __restrict__ out, short* __restrict__ oh,
                             short* __restrict__ ol) {
  __shared__ float red[4];
  int t = blockIdx.x;
  const float* row = in + (size_t)t * D_MODEL;
  int i0 = threadIdx.x, i1 = i0 + 256, i2 = i0 + 512;
  float v0 = row[i0], v1 = row[i1], v2 = row[i2];
  float ss = blk_reduce_sum(v0 * v0 + v1 * v1 + v2 * v2, red);
  float sc = rsqrtf(ss * (1.f / D_MODEL) + EPS);
  float* orow = out + (size_t)t * D_MODEL;
  float o0 = v0 * sc * w[i0], o1 = v1 * sc * w[i1], o2 = v2 * sc * w[i2];
  orow[i0] = o0; orow[i1] = o1; orow[i2] = o2;
  if (oh) {
    short h, l;
    size_t b = (size_t)t * D_MODEL;
    split1(o0, h, l); oh[b + i0] = h; ol[b + i0] = l;
    split1(o1, h, l); oh[b + i1] = h; ol[b + i1] = l;
    split1(o2, h, l); oh[b + i2] = h; ol[b + i2] = l;
  }
}

// ---------------- gated rmsnorm over 1536, optional fused bf16 split ----------------
__global__ void gated_rmsnorm_k(const float* __restrict__ y, const float* __restrict__ zx,
                                const float* __restrict__ w, float* __restrict__ out,
                                short* __restrict__ oh, short* __restrict__ ol) {
  __shared__ float red[4];
  int t = blockIdx.x;
  const float* yr = y + (size_t)t * D_INNER;
  const float* zr = zx + (size_t)t * D_IN_PROJ;   // z = first 1536 of zxbcdt
  float v[6];
  float ss = 0.f;
  #pragma unroll
  for (int i = 0; i < 6; i++) {
    int idx = threadIdx.x + i * 256;
    float val = yr[idx] * silu_f(zr[idx]);
    v[i] = val;
    ss += val * val;
  }
  ss = blk_reduce_sum(ss, red);
  float sc = rsqrtf(ss * (1.f / D_INNER) + EPS);
  float* orow = out + (size_t)t * D_INNER;
  #pragma unroll
  for (int i = 0; i < 6; i++) {
    int idx = threadIdx.x + i * 256;
    float o = v[i] * sc * w[idx];
    orow[idx] = o;
    if (oh) {
      short h, l;
      split1(o, h, l);
      oh[(size_t)t * D_INNER + idx] = h;
      ol[(size_t)t * D_INNER + idx] = l;
    }
  }
}

// ======================= GEMM (shared geometry) =======================
// C[M,N] = A[M,K] @ B[N,K]^T (+res). 128x128 tile, BK=32, 4 waves 2x2,
// v_mfma_f32_16x16x32_bf16 with hi/lo split (3 terms). Grid is M-FAST:
// bm = blockIdx.x*128 (16 blocks), bn = blockIdx.y*128. XCD = bIdx.x%8 is
// constant per M-stripe -> A tiles stay L2-resident; B panels shared in time.
#define GBM 128
#define GBN 128
#define GBK 32
#define GROWS 40            // shorts per LDS row (32 data + 8 pad)
#define GPLANE (128 * GROWS)

// ---- path A: pre-split bf16 hi/lo operands, zero conversion in loop ----
__global__ __launch_bounds__(256) void gemm_nt_hl_k(
    const short* __restrict__ Ah, const short* __restrict__ Al,
    const short* __restrict__ Bh, const short* __restrict__ Bl,
    float* __restrict__ C, const float* __restrict__ res,
    int M, int N, int K) {
  __shared__ __align__(16) short lds[4 * GPLANE];   // planes: Ah, Al, Bh, Bl
  int tid = threadIdx.x;
  int bm = blockIdx.x * GBM, bn = blockIdx.y * GBN;
  int wave = tid >> 6, lane = tid & 63;
  int wr = wave >> 1, wc = wave & 1;
  int lrow = lane & 15, kq = lane >> 4;

  // hoisted staging addresses: vec v = tid (+256): row = v>>2, k8 = v&3
  int r0 = tid >> 2, k8 = (tid & 3) * 8;
  size_t offA0 = (size_t)(bm + r0) * K + k8;
  size_t offA1 = offA0 + (size_t)64 * K;
  int brow0 = bn + r0, brow1 = brow0 + 64;
  size_t offB0 = (size_t)brow0 * K + k8;
  size_t offB1 = (size_t)brow1 * K + k8;
  bool bv0 = brow0 < N, bv1 = brow1 < N;
  int lds0 = r0 * GROWS + k8, lds1 = lds0 + 64 * GROWS;
  const bf16x8 zv = {0, 0, 0, 0, 0, 0, 0, 0};

  f32x4 acc[4][4] = {};

  for (int k0 = 0; k0 < K; k0 += GBK) {
    bf16x8 ah0 = *(const bf16x8*)&Ah[offA0 + k0];
    bf16x8 ah1 = *(const bf16x8*)&Ah[offA1 + k0];
    bf16x8 al0 = *(const bf16x8*)&Al[offA0 + k0];
    bf16x8 al1 = *(const bf16x8*)&Al[offA1 + k0];
    bf16x8 bh0 = bv0 ? *(const bf16x8*)&Bh[offB0 + k0] : zv;
    bf16x8 bh1 = bv1 ? *(const bf16x8*)&Bh[offB1 + k0] : zv;
    bf16x8 bl0 = bv0 ? *(const bf16x8*)&Bl[offB0 + k0] : zv;
    bf16x8 bl1 = bv1 ? *(const bf16x8*)&Bl[offB1 + k0] : zv;
    __syncthreads();   // prior frag reads done before overwrite
    *(bf16x8*)&lds[0 * GPLANE + lds0] = ah0;
    *(bf16x8*)&lds[0 * GPLANE + lds1] = ah1;
    *(bf16x8*)&lds[1 * GPLANE + lds0] = al0;
    *(bf16x8*)&lds[1 * GPLANE + lds1] = al1;
    *(bf16x8*)&lds[2 * GPLANE + lds0] = bh0;
    *(bf16x8*)&lds[2 * GPLANE + lds1] = bh1;
    *(bf16x8*)&lds[3 * GPLANE + lds0] = bl0;
    *(bf16x8*)&lds[3 * GPLANE + lds1] = bl1;
    __syncthreads();
    bf16x8 fah[4], fal[4], fbh[4], fbl[4];
    #pragma unroll
    for (int m = 0; m < 4; m++) {
      int aoff = (wr * 64 + m * 16 + lrow) * GROWS + kq * 8;
      fah[m] = *(const bf16x8*)&lds[0 * GPLANE + aoff];
      fal[m] = *(const bf16x8*)&lds[1 * GPLANE + aoff];
      int boff = (wc * 64 + m * 16 + lrow) * GROWS + kq * 8;
      fbh[m] = *(const bf16x8*)&lds[2 * GPLANE + boff];
      fbl[m] = *(const bf16x8*)&lds[3 * GPLANE + boff];
    }
    #pragma unroll
    for (int m = 0; m < 4; m++)
      #pragma unroll
      for (int n = 0; n < 4; n++) {
        acc[m][n] = __builtin_amdgcn_mfma_f32_16x16x32_bf16(fah[m], fbh[n], acc[m][n], 0, 0, 0);
        acc[m][n] = __builtin_amdgcn_mfma_f32_16x16x32_bf16(fah[m], fbl[n], acc[m][n], 0, 0, 0);
        acc[m][n] = __builtin_amdgcn_mfma_f32_16x16x32_bf16(fal[m], fbh[n], acc[m][n], 0, 0, 0);
      }
  }

  // C write: col = lane&15, row = (lane>>4)*4 + reg  (m89/m91 layout)
  #pragma unroll
  for (int m = 0; m < 4; m++) {
    int rbase = bm + wr * 64 + m * 16 + kq * 4;
    #pragma unroll
    for (int n = 0; n < 4; n++) {
      int col = bn + wc * 64 + n * 16 + lrow;
      if (col < N) {
        #pragma unroll
        for (int j = 0; j < 4; j++) {
          size_t ci = (size_t)(rbase + j) * N + col;
          float v = acc[m][n][j];
          if (res) v += res[ci];
          C[ci] = v;
        }
      }
    }
  }
}

// ---- path B fallback: fp32 operands, convert-in-kernel (verified config) ----
__global__ __launch_bounds__(256) void gemm_nt_mfma_k(
    const float* __restrict__ A, const float* __restrict__ B,
    float* __restrict__ C, const float* __restrict__ res,
    int M, int N, int K) {
  __shared__ __align__(16) short lds[4 * GPLANE];
  int tid = threadIdx.x;
  int bm = blockIdx.x * GBM, bn = blockIdx.y * GBN;   // M-fast grid
  int wave = tid >> 6, lane = tid & 63;
  int wr = wave >> 1, wc = wave & 1;
  int lrow = lane & 15, kq = lane >> 4;

  f32x4 acc[4][4] = {};

  for (int k0 = 0; k0 < K; k0 += GBK) {
    float4 ra[4], rb[4];
    #pragma unroll
    for (int r = 0; r < 4; r++) {
      int flat = (r << 8) + tid;
      int row = flat >> 3;
      int q = flat & 7;
      ra[r] = *(const float4*)&A[(size_t)(bm + row) * K + k0 + (q << 2)];
      int brow = bn + row;
      if (brow < N)
        rb[r] = *(const float4*)&B[(size_t)brow * K + k0 + (q << 2)];
      else
        rb[r] = make_float4(0.f, 0.f, 0.f, 0.f);
    }
    __syncthreads();
    #pragma unroll
    for (int r = 0; r < 4; r++) {
      int flat = (r << 8) + tid;
      int row = flat >> 3;
      int q = flat & 7;
      int eoff = row * GROWS + (q << 2);
      bf16x4 h4, l4;
      split4(ra[r], h4, l4);
      *(bf16x4*)&lds[0 * GPLANE + eoff] = h4;
      *(bf16x4*)&lds[1 * GPLANE + eoff] = l4;
      split4(rb[r], h4, l4);
      *(bf16x4*)&lds[2 * GPLANE + eoff] = h4;
      *(bf16x4*)&lds[3 * GPLANE + eoff] = l4;
    }
    __syncthreads();
    bf16x8 ah[4], al[4], bh[4], bl[4];
    #pragma unroll
    for (int m = 0; m < 4; m++) {
      int aoff = (wr * 64 + m * 16 + lrow) * GROWS + kq * 8;
      ah[m] = *(const bf16x8*)&lds[0 * GPLANE + aoff];
      al[m] = *(const bf16x8*)&lds[1 * GPLANE + aoff];
      int boff = (wc * 64 + m * 16 + lrow) * GROWS + kq * 8;
      bh[m] = *(const bf16x8*)&lds[2 * GPLANE + boff];
      bl[m] = *(const bf16x8*)&lds[3 * GPLANE + boff];
    }
    #pragma unroll
    for (int m = 0; m < 4; m++)
      #pragma unroll
      for (int n = 0; n < 4; n++) {
        acc[m][n] = __builtin_amdgcn_mfma_f32_16x16x32_bf16(ah[m], bh[n], acc[m][n], 0, 0, 0);
        acc[m][n] = __builtin_amdgcn_mfma_f32_16x16x32_bf16(ah[m], bl[n], acc[m][n], 0, 0, 0);
        acc[m][n] = __builtin_amdgcn_mfma_f32_16x16x32_bf16(al[m], bh[n], acc[m][n], 0, 0, 0);
      }
  }

  #pragma unroll
  for (int m = 0; m < 4; m++) {
    int rbase = bm + wr * 64 + m * 16 + kq * 4;
    #pragma unroll
    for (int n = 0; n < 4; n++) {
      int col = bn + wc * 64 + n * 16 + lrow;
      if (col < N) {
        #pragma unroll
        for (int j = 0; j < 4; j++) {
          size_t ci = (size_t)(rbase + j) * N + col;
          float v = acc[m][n][j];
          if (res) v += res[ci];
          C[ci] = v;
        }
      }
    }
  }
}

// ---------------- depthwise causal conv4 + silu on xBC; softplus dt ----------------
__global__ void conv_dt_k(const float* __restrict__ zx, const float* __restrict__ cw,
                          const float* __restrict__ cb, const float* __restrict__ dtb,
                          float* __restrict__ xbc, float* __restrict__ dtbuf) {
  int idx = blockIdx.x * 256 + threadIdx.x;     // over SEQLEN*CONV_DIM
  int t = idx / CONV_DIM, ch = idx - t * CONV_DIM;
  float acc = cb[ch];
  #pragma unroll
  for (int k = 0; k < 4; k++) {
    int tt = t - 3 + k;
    if (tt >= 0) acc += cw[ch * 4 + k] * zx[(size_t)tt * D_IN_PROJ + D_INNER + ch];
  }
  xbc[(size_t)t * CONV_DIM + ch] = silu_f(acc);
  if (ch < NHEADS) {
    float raw = zx[(size_t)t * D_IN_PROJ + (D_INNER + CONV_DIM) + ch] + dtb[ch];
    dtbuf[t * NHEADS + ch] = (raw > 20.f) ? raw : log1pf(expf(raw));
  }
}

// ---------------- SSD phase 1 ----------------
__global__ __launch_bounds__(256) void ssd_phase1_k(
    const float* __restrict__ xbc, const float* __restrict__ dtbuf,
    const float* __restrict__ A_log, float* __restrict__ ybuf,
    float* __restrict__ states, float* __restrict__ acum_g) {
  __shared__ float Bs[64][129];
  __shared__ float Cs[64][129];
  __shared__ float Xs[64][65];
  __shared__ float Gs[64][65];
  __shared__ float ac[64], dts[64], decay[64];
  int c = blockIdx.x, h = blockIdx.y, tid = threadIdx.x;

  if (tid < 64) dts[tid] = dtbuf[(c * 64 + tid) * NHEADS + h];
  __syncthreads();
  if (tid == 0) {
    float Ah = -expf(A_log[h]);
    float s = 0.f;
    for (int l = 0; l < 64; l++) { s += Ah * dts[l]; ac[l] = s; }
  }
  __syncthreads();
  if (tid < 64) {
    decay[tid] = expf(ac[63] - ac[tid]);
    acum_g[(h * NCHUNK + c) * 64 + tid] = ac[tid];
  }
  for (int idx = tid; idx < 64 * 128; idx += 256) {
    int l = idx >> 7, n = idx & 127;
    const float* row = xbc + (size_t)(c * 64 + l) * CONV_DIM;
    Bs[l][n] = row[D_INNER + n];
    Cs[l][n] = row[D_INNER + D_STATE + n];
  }
  for (int idx = tid; idx < 64 * 64; idx += 256) {
    int l = idx >> 6, p = idx & 63;
    Xs[l][p] = xbc[(size_t)(c * 64 + l) * CONV_DIM + h * 64 + p] * dts[l];
  }
  __syncthreads();
  for (int idx = tid; idx < 64 * 128; idx += 256) {
    int p = idx >> 7, n = idx & 127;
    float s = 0.f;
    for (int l = 0; l < 64; l++) s += Xs[l][p] * decay[l] * Bs[l][n];
    states[((size_t)(h * NCHUNK + c) * 64 + p) * 128 + n] = s;
  }
  for (int idx = tid; idx < 64 * 64; idx += 256) {
    int i = idx >> 6, j = idx & 63;
    float g = 0.f;
    if (j <= i) {
      for (int n = 0; n < 128; n++) g += Cs[i][n] * Bs[j][n];
      g *= expf(ac[i] - ac[j]);
    }
    Gs[i][j] = g;
  }
  __syncthreads();
  for (int idx = tid; idx < 64 * 64; idx += 256) {
    int i = idx >> 6, p = idx & 63;
    float yv = 0.f;
    for (int j = 0; j <= i; j++) yv += Gs[i][j] * Xs[j][p];
    ybuf[(size_t)(c * 64 + i) * D_INNER + h * 64 + p] = yv;
  }
}

// ---------------- SSD phase 2: inter-chunk scan ----------------
__global__ void ssd_scan_k(const float* __restrict__ states, const float* __restrict__ acum_g,
                           float* __restrict__ sprefix) {
  int h = blockIdx.x, tid = threadIdx.x;
  float S[32];
  #pragma unroll
  for (int i = 0; i < 32; i++) S[i] = 0.f;
  for (int c = 0; c < NCHUNK; c++) {
    size_t base = (size_t)(h * NCHUNK + c) * 8192;
    float d = expf(acum_g[(h * NCHUNK + c) * 64 + 63]);
    #pragma unroll
    for (int i = 0; i < 32; i++) {
      size_t off = base + tid + i * 256;
      sprefix[off] = S[i];
      S[i] = d * S[i] + states[off];
    }
  }
}

// ---------------- SSD phase 3 ----------------
__global__ __launch_bounds__(256) void ssd_phase3_k(
    const float* __restrict__ xbc, const float* __restrict__ sprefix,
    const float* __restrict__ acum_g, const float* __restrict__ Dv,
    float* __restrict__ ybuf) {
  __shared__ float Sp[64][129];
  __shared__ float Cs[64][129];
  __shared__ float ac[64];
  int c = blockIdx.x, h = blockIdx.y, tid = threadIdx.x;
  if (tid < 64) ac[tid] = acum_g[(h * NCHUNK + c) * 64 + tid];
  for (int idx = tid; idx < 64 * 128; idx += 256) {
    int p = idx >> 7, n = idx & 127;
    Sp[p][n] = sprefix[((size_t)(h * NCHUNK + c) * 64 + p) * 128 + n];
    Cs[p][n] = xbc[(size_t)(c * 64 + p) * CONV_DIM + D_INNER + D_STATE + n];
  }
  __syncthreads();
  float Dh = Dv[h];
  for (int idx = tid; idx < 64 * 64; idx += 256) {
    int l = idx >> 6, p = idx & 63;
    float s = 0.f;
    for (int n = 0; n < 128; n++) s += Cs[l][n] * Sp[p][n];
    size_t yi = (size_t)(c * 64 + l) * D_INNER + h * 64 + p;
    float xv = xbc[(size_t)(c * 64 + l) * CONV_DIM + h * 64 + p];
    ybuf[yi] += expf(ac[l]) * s + xv * Dh;
  }
}

// ---------------- host launch ----------------
extern "C" void kernel_launch(void* const* d_in, const int* in_sizes, int n_in,
                              void* d_out, int out_size, void* d_ws, size_t ws_size,
                              hipStream_t stream) {
  const int*   ids  = (const int*)d_in[0];
  const float* emb  = (const float*)d_in[1];
  const float* ipw  = (const float*)d_in[2];   // (4, 3352, 768)
  const float* cw   = (const float*)d_in[3];   // (4, 1792, 4)
  const float* cb   = (const float*)d_in[4];   // (4, 1792)
  const float* dtb  = (const float*)d_in[5];   // (4, 24)
  const float* alog = (const float*)d_in[6];   // (4, 24)
  const float* Dv   = (const float*)d_in[7];   // (4, 24)
  const float* mnw  = (const float*)d_in[8];   // (4, 1536)
  const float* opw  = (const float*)d_in[9];   // (4, 768, 1536)
  const float* lnw  = (const float*)d_in[10];  // (4, 768)
  const float* nfw  = (const float*)d_in[11];  // (768,)
  float* out = (float*)d_out;

  const size_t F_X   = (size_t)SEQLEN * D_MODEL;        // 1,572,864
  const size_t F_UHL = F_X / 2;                          // bf16 plane in floats
  const size_t F_EMB = (size_t)VOCAB * D_MODEL / 2;      // 19,310,592
  // path-A ws need: x, u, uh, ul, emb_h, emb_l
  const size_t NEED_A = (F_X * 2 + F_UHL * 2 + F_EMB * 2) * sizeof(float);

  const size_t BIG_F = (size_t)SEQLEN * D_IN_PROJ + (size_t)SEQLEN * CONV_DIM +
                       (size_t)SEQLEN * NHEADS + (size_t)SEQLEN * D_INNER +
                       2ull * NHEADS * NCHUNK * CHUNK * D_STATE +
                       (size_t)NHEADS * NCHUNK * CHUNK;

  float* x = (float*)d_ws;
  float* u = x + F_X;

  bool pathA = ws_size >= NEED_A;

  if (pathA) {
    // ---- ws: persistent-to-the-end buffers ----
    short* uh    = (short*)(u + F_X);
    short* ul    = uh + F_X;
    short* emb_h = (short*)((float*)d_ws + 2 * F_X + 2 * F_UHL);
    short* emb_l = emb_h + (size_t)VOCAB * D_MODEL;

    // ---- d_out scratch: dead until the final vocab GEMM ----
    float* sb = (float*)d_out;
    short* gh   = (short*)sb;                       // 2048x1536 bf16
    short* gl   = gh + (size_t)SEQLEN * D_INNER;
    short* ipwh = gl + (size_t)SEQLEN * D_INNER;    // 4x3352x768 bf16
    short* ipwl = ipwh + (size_t)N_LAYER * D_IN_PROJ * D_MODEL;
    short* opwh = ipwl + (size_t)N_LAYER * D_IN_PROJ * D_MODEL;
    short* opwl = opwh + (size_t)N_LAYER * D_MODEL * D_INNER;
    float* big  = (float*)(opwl + (size_t)N_LAYER * D_MODEL * D_INNER);
    float* zx      = big;
    float* xbc     = zx + (size_t)SEQLEN * D_IN_PROJ;
    float* dtbuf   = xbc + (size_t)SEQLEN * CONV_DIM;
    float* ybuf    = dtbuf + (size_t)SEQLEN * NHEADS;
    float* states  = ybuf + (size_t)SEQLEN * D_INNER;
    float* sprefix = states + (size_t)NHEADS * NCHUNK * CHUNK * D_STATE;
    float* acum    = sprefix + (size_t)NHEADS * NCHUNK * CHUNK * D_STATE;

    // one-time weight/emb splits (~70 us of pure BW)
    split_k<<<4096, 256, 0, stream>>>(emb, emb_h, emb_l, (long)VOCAB * D_MODEL / 4);
    split_k<<<2048, 256, 0, stream>>>(ipw, ipwh, ipwl, (long)N_LAYER * D_IN_PROJ * D_MODEL / 4);
    split_k<<<1024, 256, 0, stream>>>(opw, opwh, opwl, (long)N_LAYER * D_MODEL * D_INNER / 4);

    embed_k<<<SEQLEN, 256, 0, stream>>>(ids, emb, x);

    for (int i = 0; i < N_LAYER; i++) {
      rmsnorm768_k<<<SEQLEN, 256, 0, stream>>>(x, lnw + i * D_MODEL, u, uh, ul);
      gemm_nt_hl_k<<<dim3(SEQLEN / GBM, (D_IN_PROJ + GBN - 1) / GBN), 256, 0, stream>>>(
          uh, ul, ipwh + (size_t)i * D_IN_PROJ * D_MODEL, ipwl + (size_t)i * D_IN_PROJ * D_MODEL,
          zx, nullptr, SEQLEN, D_IN_PROJ, D_MODEL);
      conv_dt_k<<<(SEQLEN * CONV_DIM) / 256, 256, 0, stream>>>(
          zx, cw + (size_t)i * CONV_DIM * D_CONV, cb + (size_t)i * CONV_DIM,
          dtb + i * NHEADS, xbc, dtbuf);
      ssd_phase1_k<<<dim3(NCHUNK, NHEADS), 256, 0, stream>>>(
          xbc, dtbuf, alog + i * NHEADS, ybuf, states, acum);
      ssd_scan_k<<<NHEADS, 256, 0, stream>>>(states, acum, sprefix);
      ssd_phase3_k<<<dim3(NCHUNK, NHEADS), 256, 0, stream>>>(
          xbc, sprefix, acum, Dv + i * NHEADS, ybuf);
      gated_rmsnorm_k<<<SEQLEN, 256, 0, stream>>>(ybuf, zx, mnw + i * D_INNER, xbc, gh, gl);
      gemm_nt_hl_k<<<dim3(SEQLEN / GBM, D_MODEL / GBN), 256, 0, stream>>>(
          gh, gl, opwh + (size_t)i * D_MODEL * D_INNER, opwl + (size_t)i * D_MODEL * D_INNER,
          x, x, SEQLEN, D_MODEL, D_INNER);
    }

    rmsnorm768_k<<<SEQLEN, 256, 0, stream>>>(x, nfw, u, uh, ul);
    gemm_nt_hl_k<<<dim3(SEQLEN / GBM, (VOCAB + GBN - 1) / GBN), 256, 0, stream>>>(
        uh, ul, emb_h, emb_l, out, nullptr, SEQLEN, VOCAB, D_MODEL);
    return;
  }

  // ================= path B: verified fallback (convert-in-kernel) =================
  const size_t SMALL_F = 2ull * F_X;
  float* big = (ws_size >= (SMALL_F + BIG_F) * sizeof(float))
                   ? (u + F_X)
                   : (float*)d_out;
  float* zx      = big;
  float* xbc     = zx + (size_t)SEQLEN * D_IN_PROJ;
  float* dtbuf   = xbc + (size_t)SEQLEN * CONV_DIM;
  float* ybuf    = dtbuf + (size_t)SEQLEN * NHEADS;
  float* states  = ybuf + (size_t)SEQLEN * D_INNER;
  float* sprefix = states + (size_t)NHEADS * NCHUNK * CHUNK * D_STATE;
  float* acum    = sprefix + (size_t)NHEADS * NCHUNK * CHUNK * D_STATE;

  embed_k<<<SEQLEN, 256, 0, stream>>>(ids, emb, x);

  for (int i = 0; i < N_LAYER; i++) {
    rmsnorm768_k<<<SEQLEN, 256, 0, stream>>>(x, lnw + i * D_MODEL, u, nullptr, nullptr);
    gemm_nt_mfma_k<<<dim3(SEQLEN / GBM, (D_IN_PROJ + GBN - 1) / GBN), 256, 0, stream>>>(
        u, ipw + (size_t)i * D_IN_PROJ * D_MODEL, zx, nullptr, SEQLEN, D_IN_PROJ, D_MODEL);
    conv_dt_k<<<(SEQLEN * CONV_DIM) / 256, 256, 0, stream>>>(
        zx, cw + (size_t)i * CONV_DIM * D_CONV, cb + (size_t)i * CONV_DIM,
        dtb + i * NHEADS, xbc, dtbuf);
    ssd_phase1_k<<<dim3(NCHUNK, NHEADS), 256, 0, stream>>>(
        xbc, dtbuf, alog + i * NHEADS, ybuf, states, acum);
    ssd_scan_k<<<NHEADS, 256, 0, stream>>>(states, acum, sprefix);
    ssd_phase3_k<<<dim3(NCHUNK, NHEADS), 256, 0, stream>>>(
        xbc, sprefix, acum, Dv + i * NHEADS, ybuf);
    gated_rmsnorm_k<<<SEQLEN, 256, 0, stream>>>(ybuf, zx, mnw + i * D_INNER, xbc, nullptr, nullptr);
    gemm_nt_mfma_k<<<dim3(SEQLEN / GBM, D_MODEL / GBN), 256, 0, stream>>>(
        xbc, opw + (size_t)i * D_MODEL * D_INNER, x, x, SEQLEN, D_MODEL, D_INNER);
  }

  rmsnorm768_k<<<SEQLEN, 256, 0, stream>>>(x, nfw, u, nullptr, nullptr);
  gemm_nt_mfma_k<<<dim3(SEQLEN / GBM, (VOCAB + GBN - 1) / GBN), 256, 0, stream>>>(
      u, emb, out, nullptr, SEQLEN, VOCAB, D_MODEL);
}

// Round 3
// 2077.083 us; speedup vs baseline: 1.4565x; 1.4135x over previous
//
#include <hip/hip_runtime.h>
#include <math.h>

#define D_MODEL   768
#define N_LAYER   4
#define D_STATE   128
#define D_CONV    4
#define HEADDIM   64
#define CHUNK     64
#define NCHUNK    32      // SEQLEN / CHUNK
#define VOCAB     50288
#define D_INNER   1536
#define NHEADS    24
#define CONV_DIM  1792    // D_INNER + 2*D_STATE
#define D_IN_PROJ 3352    // 2*D_INNER + 2*D_STATE + NHEADS
#define SEQLEN    2048
#define EPS       1e-5f

typedef float f32x4 __attribute__((ext_vector_type(4)));
typedef short bf16x8 __attribute__((ext_vector_type(8)));
typedef short bf16x4 __attribute__((ext_vector_type(4)));

// ---------------- block-wide reduction (256 threads = 4 waves) ----------------
__device__ __forceinline__ float blk_reduce_sum(float v, float* red) {
  #pragma unroll
  for (int off = 32; off > 0; off >>= 1) v += __shfl_down(v, off, 64);
  if ((threadIdx.x & 63) == 0) red[threadIdx.x >> 6] = v;
  __syncthreads();
  float s = red[0] + red[1] + red[2] + red[3];
  __syncthreads();
  return s;
}

__device__ __forceinline__ float silu_f(float x) {
  return x / (1.f + expf(-x));
}

// RNE fp32 -> bf16 (top 16 bits)
__device__ __forceinline__ unsigned short bf16_rne(float x) {
  unsigned int u = __builtin_bit_cast(unsigned int, x);
  u += 0x7FFFu + ((u >> 16) & 1u);
  return (unsigned short)(u >> 16);
}

// split fp32 x into hi+lo bf16 pair: x ~= hi + lo, |x-hi-lo| <= 2^-18 |x|
__device__ __forceinline__ void split1(float x, short& h, short& l) {
  unsigned int u = __builtin_bit_cast(unsigned int, x);
  unsigned int rh = u + 0x7FFFu + ((u >> 16) & 1u);
  h = (short)(unsigned short)(rh >> 16);
  float hf = __builtin_bit_cast(float, rh & 0xFFFF0000u);
  l = (short)bf16_rne(x - hf);
}

__device__ __forceinline__ void split4(float4 v, bf16x4& h, bf16x4& l) {
  float vv[4] = {v.x, v.y, v.z, v.w};
  #pragma unroll
  for (int i = 0; i < 4; i++) {
    short hs, ls;
    split1(vv[i], hs, ls);
    h[i] = hs;
    l[i] = ls;
  }
}

// ---------------- bulk fp32 -> (hi,lo) bf16 splitter ----------------
__global__ void split_k(const float* __restrict__ src, short* __restrict__ h,
                        short* __restrict__ l, long n4) {
  long i = (long)blockIdx.x * 256 + threadIdx.x;
  long stride = (long)gridDim.x * 256;
  for (; i < n4; i += stride) {
    float4 v = ((const float4*)src)[i];
    bf16x4 hh, ll;
    split4(v, hh, ll);
    ((bf16x4*)h)[i] = hh;
    ((bf16x4*)l)[i] = ll;
  }
}

// ---------------- embedding gather ----------------
__global__ void embed_k(const int* __restrict__ ids, const float* __restrict__ emb,
                        float* __restrict__ x) {
  int t = blockIdx.x;
  size_t src = (size_t)ids[t] * D_MODEL;
  for (int i = threadIdx.x; i < D_MODEL; i += 256)
    x[(size_t)t * D_MODEL + i] = emb[src + i];
}

// ---------------- rmsnorm over 768, optional fused bf16 split output ----------------
__global__ void rmsnorm768_k(const float* __restrict__ in, const float* __restrict__ w,
                             float* __restrict__ out, short* __restrict__ oh,
                             short* __restrict__ ol) {
  __shared__ float red[4];
  int t = blockIdx.x;
  const float* row = in + (size_t)t * D_MODEL;
  int i0 = threadIdx.x, i1 = i0 + 256, i2 = i0 + 512;
  float v0 = row[i0], v1 = row[i1], v2 = row[i2];
  float ss = blk_reduce_sum(v0 * v0 + v1 * v1 + v2 * v2, red);
  float sc = rsqrtf(ss * (1.f / D_MODEL) + EPS);
  float* orow = out + (size_t)t * D_MODEL;
  float o0 = v0 * sc * w[i0], o1 = v1 * sc * w[i1], o2 = v2 * sc * w[i2];
  orow[i0] = o0; orow[i1] = o1; orow[i2] = o2;
  if (oh) {
    short h, l;
    size_t b = (size_t)t * D_MODEL;
    split1(o0, h, l); oh[b + i0] = h; ol[b + i0] = l;
    split1(o1, h, l); oh[b + i1] = h; ol[b + i1] = l;
    split1(o2, h, l); oh[b + i2] = h; ol[b + i2] = l;
  }
}

// ---------------- gated rmsnorm over 1536, optional fused bf16 split ----------------
__global__ void gated_rmsnorm_k(const float* __restrict__ y, const float* __restrict__ zx,
                                const float* __restrict__ w, float* __restrict__ out,
                                short* __restrict__ oh, short* __restrict__ ol) {
  __shared__ float red[4];
  int t = blockIdx.x;
  const float* yr = y + (size_t)t * D_INNER;
  const float* zr = zx + (size_t)t * D_IN_PROJ;   // z = first 1536 of zxbcdt
  float v[6];
  float ss = 0.f;
  #pragma unroll
  for (int i = 0; i < 6; i++) {
    int idx = threadIdx.x + i * 256;
    float val = yr[idx] * silu_f(zr[idx]);
    v[i] = val;
    ss += val * val;
  }
  ss = blk_reduce_sum(ss, red);
  float sc = rsqrtf(ss * (1.f / D_INNER) + EPS);
  float* orow = out + (size_t)t * D_INNER;
  #pragma unroll
  for (int i = 0; i < 6; i++) {
    int idx = threadIdx.x + i * 256;
    float o = v[i] * sc * w[idx];
    orow[idx] = o;
    if (oh) {
      short h, l;
      split1(o, h, l);
      oh[(size_t)t * D_INNER + idx] = h;
      ol[(size_t)t * D_INNER + idx] = l;
    }
  }
}

// ======================= GEMM (shared geometry) =======================
#define GBM 128
#define GBN 128
#define GBK 32
#define GROWS 40            // shorts per LDS row (32 data + 8 pad)
#define GPLANE (128 * GROWS)

// ---- path A: pre-split bf16 hi/lo operands, zero conversion in loop ----
__global__ __launch_bounds__(256) void gemm_nt_hl_k(
    const short* __restrict__ Ah, const short* __restrict__ Al,
    const short* __restrict__ Bh, const short* __restrict__ Bl,
    float* __restrict__ C, const float* __restrict__ res,
    int M, int N, int K) {
  __shared__ __align__(16) short lds[4 * GPLANE];   // planes: Ah, Al, Bh, Bl
  int tid = threadIdx.x;
  int bm = blockIdx.x * GBM, bn = blockIdx.y * GBN;
  int wave = tid >> 6, lane = tid & 63;
  int wr = wave >> 1, wc = wave & 1;
  int lrow = lane & 15, kq = lane >> 4;

  int r0 = tid >> 2, k8 = (tid & 3) * 8;
  size_t offA0 = (size_t)(bm + r0) * K + k8;
  size_t offA1 = offA0 + (size_t)64 * K;
  int brow0 = bn + r0, brow1 = brow0 + 64;
  size_t offB0 = (size_t)brow0 * K + k8;
  size_t offB1 = (size_t)brow1 * K + k8;
  bool bv0 = brow0 < N, bv1 = brow1 < N;
  int lds0 = r0 * GROWS + k8, lds1 = lds0 + 64 * GROWS;
  const bf16x8 zv = {0, 0, 0, 0, 0, 0, 0, 0};

  f32x4 acc[4][4] = {};

  for (int k0 = 0; k0 < K; k0 += GBK) {
    bf16x8 ah0 = *(const bf16x8*)&Ah[offA0 + k0];
    bf16x8 ah1 = *(const bf16x8*)&Ah[offA1 + k0];
    bf16x8 al0 = *(const bf16x8*)&Al[offA0 + k0];
    bf16x8 al1 = *(const bf16x8*)&Al[offA1 + k0];
    bf16x8 bh0 = bv0 ? *(const bf16x8*)&Bh[offB0 + k0] : zv;
    bf16x8 bh1 = bv1 ? *(const bf16x8*)&Bh[offB1 + k0] : zv;
    bf16x8 bl0 = bv0 ? *(const bf16x8*)&Bl[offB0 + k0] : zv;
    bf16x8 bl1 = bv1 ? *(const bf16x8*)&Bl[offB1 + k0] : zv;
    __syncthreads();
    *(bf16x8*)&lds[0 * GPLANE + lds0] = ah0;
    *(bf16x8*)&lds[0 * GPLANE + lds1] = ah1;
    *(bf16x8*)&lds[1 * GPLANE + lds0] = al0;
    *(bf16x8*)&lds[1 * GPLANE + lds1] = al1;
    *(bf16x8*)&lds[2 * GPLANE + lds0] = bh0;
    *(bf16x8*)&lds[2 * GPLANE + lds1] = bh1;
    *(bf16x8*)&lds[3 * GPLANE + lds0] = bl0;
    *(bf16x8*)&lds[3 * GPLANE + lds1] = bl1;
    __syncthreads();
    bf16x8 fah[4], fal[4], fbh[4], fbl[4];
    #pragma unroll
    for (int m = 0; m < 4; m++) {
      int aoff = (wr * 64 + m * 16 + lrow) * GROWS + kq * 8;
      fah[m] = *(const bf16x8*)&lds[0 * GPLANE + aoff];
      fal[m] = *(const bf16x8*)&lds[1 * GPLANE + aoff];
      int boff = (wc * 64 + m * 16 + lrow) * GROWS + kq * 8;
      fbh[m] = *(const bf16x8*)&lds[2 * GPLANE + boff];
      fbl[m] = *(const bf16x8*)&lds[3 * GPLANE + boff];
    }
    #pragma unroll
    for (int m = 0; m < 4; m++)
      #pragma unroll
      for (int n = 0; n < 4; n++) {
        acc[m][n] = __builtin_amdgcn_mfma_f32_16x16x32_bf16(fah[m], fbh[n], acc[m][n], 0, 0, 0);
        acc[m][n] = __builtin_amdgcn_mfma_f32_16x16x32_bf16(fah[m], fbl[n], acc[m][n], 0, 0, 0);
        acc[m][n] = __builtin_amdgcn_mfma_f32_16x16x32_bf16(fal[m], fbh[n], acc[m][n], 0, 0, 0);
      }
  }

  #pragma unroll
  for (int m = 0; m < 4; m++) {
    int rbase = bm + wr * 64 + m * 16 + kq * 4;
    #pragma unroll
    for (int n = 0; n < 4; n++) {
      int col = bn + wc * 64 + n * 16 + lrow;
      if (col < N) {
        #pragma unroll
        for (int j = 0; j < 4; j++) {
          size_t ci = (size_t)(rbase + j) * N + col;
          float v = acc[m][n][j];
          if (res) v += res[ci];
          C[ci] = v;
        }
      }
    }
  }
}

// ---- path B fallback: fp32 operands, convert-in-kernel ----
__global__ __launch_bounds__(256) void gemm_nt_mfma_k(
    const float* __restrict__ A, const float* __restrict__ B,
    float* __restrict__ C, const float* __restrict__ res,
    int M, int N, int K) {
  __shared__ __align__(16) short lds[4 * GPLANE];
  int tid = threadIdx.x;
  int bm = blockIdx.x * GBM, bn = blockIdx.y * GBN;
  int wave = tid >> 6, lane = tid & 63;
  int wr = wave >> 1, wc = wave & 1;
  int lrow = lane & 15, kq = lane >> 4;

  f32x4 acc[4][4] = {};

  for (int k0 = 0; k0 < K; k0 += GBK) {
    float4 ra[4], rb[4];
    #pragma unroll
    for (int r = 0; r < 4; r++) {
      int flat = (r << 8) + tid;
      int row = flat >> 3;
      int q = flat & 7;
      ra[r] = *(const float4*)&A[(size_t)(bm + row) * K + k0 + (q << 2)];
      int brow = bn + row;
      if (brow < N)
        rb[r] = *(const float4*)&B[(size_t)brow * K + k0 + (q << 2)];
      else
        rb[r] = make_float4(0.f, 0.f, 0.f, 0.f);
    }
    __syncthreads();
    #pragma unroll
    for (int r = 0; r < 4; r++) {
      int flat = (r << 8) + tid;
      int row = flat >> 3;
      int q = flat & 7;
      int eoff = row * GROWS + (q << 2);
      bf16x4 h4, l4;
      split4(ra[r], h4, l4);
      *(bf16x4*)&lds[0 * GPLANE + eoff] = h4;
      *(bf16x4*)&lds[1 * GPLANE + eoff] = l4;
      split4(rb[r], h4, l4);
      *(bf16x4*)&lds[2 * GPLANE + eoff] = h4;
      *(bf16x4*)&lds[3 * GPLANE + eoff] = l4;
    }
    __syncthreads();
    bf16x8 ah[4], al[4], bh[4], bl[4];
    #pragma unroll
    for (int m = 0; m < 4; m++) {
      int aoff = (wr * 64 + m * 16 + lrow) * GROWS + kq * 8;
      ah[m] = *(const bf16x8*)&lds[0 * GPLANE + aoff];
      al[m] = *(const bf16x8*)&lds[1 * GPLANE + aoff];
      int boff = (wc * 64 + m * 16 + lrow) * GROWS + kq * 8;
      bh[m] = *(const bf16x8*)&lds[2 * GPLANE + boff];
      bl[m] = *(const bf16x8*)&lds[3 * GPLANE + boff];
    }
    #pragma unroll
    for (int m = 0; m < 4; m++)
      #pragma unroll
      for (int n = 0; n < 4; n++) {
        acc[m][n] = __builtin_amdgcn_mfma_f32_16x16x32_bf16(ah[m], bh[n], acc[m][n], 0, 0, 0);
        acc[m][n] = __builtin_amdgcn_mfma_f32_16x16x32_bf16(ah[m], bl[n], acc[m][n], 0, 0, 0);
        acc[m][n] = __builtin_amdgcn_mfma_f32_16x16x32_bf16(al[m], bh[n], acc[m][n], 0, 0, 0);
      }
  }

  #pragma unroll
  for (int m = 0; m < 4; m++) {
    int rbase = bm + wr * 64 + m * 16 + kq * 4;
    #pragma unroll
    for (int n = 0; n < 4; n++) {
      int col = bn + wc * 64 + n * 16 + lrow;
      if (col < N) {
        #pragma unroll
        for (int j = 0; j < 4; j++) {
          size_t ci = (size_t)(rbase + j) * N + col;
          float v = acc[m][n][j];
          if (res) v += res[ci];
          C[ci] = v;
        }
      }
    }
  }
}

// ---------------- depthwise causal conv4 + silu on xBC; softplus dt ----------------
__global__ void conv_dt_k(const float* __restrict__ zx, const float* __restrict__ cw,
                          const float* __restrict__ cb, const float* __restrict__ dtb,
                          float* __restrict__ xbc, float* __restrict__ dtbuf) {
  int idx = blockIdx.x * 256 + threadIdx.x;     // over SEQLEN*CONV_DIM
  int t = idx / CONV_DIM, ch = idx - t * CONV_DIM;
  float acc = cb[ch];
  #pragma unroll
  for (int k = 0; k < 4; k++) {
    int tt = t - 3 + k;
    if (tt >= 0) acc += cw[ch * 4 + k] * zx[(size_t)tt * D_IN_PROJ + D_INNER + ch];
  }
  xbc[(size_t)t * CONV_DIM + ch] = silu_f(acc);
  if (ch < NHEADS) {
    float raw = zx[(size_t)t * D_IN_PROJ + (D_INNER + CONV_DIM) + ch] + dtb[ch];
    dtbuf[t * NHEADS + ch] = (raw > 20.f) ? raw : log1pf(expf(raw));
  }
}

// ---------------- SSD phase 1 (register-tiled, float4-vectorized) ----------------
// per (chunk c, head h): states[p][n], Y_diag, acum. 256 threads.
// LDS: Bs[64][128] (row reads lane-consecutive + broadcasts),
//      Cs[64][132] (stride 132 -> bank-span period 8, conflict-free float4 column-of-rows),
//      Xs[64][64] (broadcast only), Gs[64][68]. Yt reuses Cs.
__global__ __launch_bounds__(256) void ssd_phase1_k(
    const float* __restrict__ xbc, const float* __restrict__ dtbuf,
    const float* __restrict__ A_log, float* __restrict__ ybuf,
    float* __restrict__ states, float* __restrict__ acum_g) {
  __shared__ float Bs[64][128];
  __shared__ float Cs[64][132];
  __shared__ float Xs[64][64];
  __shared__ float Gs[64][68];
  __shared__ float ac[64], dts[64], decay[64];
  int c = blockIdx.x, h = blockIdx.y, tid = threadIdx.x;
  int lane = tid & 63;

  if (tid < 64) dts[tid] = dtbuf[(c * 64 + tid) * NHEADS + h];
  // stage B, C rows (float4)
  for (int idx = tid; idx < 64 * 32; idx += 256) {
    int l = idx >> 5, n4 = (idx & 31) << 2;
    const float* row = xbc + (size_t)(c * 64 + l) * CONV_DIM + D_INNER;
    *(float4*)&Bs[l][n4] = *(const float4*)(row + n4);
    *(float4*)&Cs[l][n4] = *(const float4*)(row + D_STATE + n4);
  }
  __syncthreads();   // dts visible
  if (tid < 64) {
    float Ah = -expf(A_log[h]);
    float v = Ah * dts[lane];
    #pragma unroll
    for (int off = 1; off < 64; off <<= 1) {
      float o = __shfl_up(v, off, 64);
      if (lane >= off) v += o;
    }
    ac[lane] = v;
    acum_g[(h * NCHUNK + c) * 64 + lane] = v;
    float ac63 = __shfl(v, 63, 64);
    decay[lane] = expf(ac63 - v);
  }
  // stage X (needs dts)
  for (int idx = tid; idx < 64 * 16; idx += 256) {
    int l = idx >> 4, p4 = (idx & 15) << 2;
    float4 xv = *(const float4*)&xbc[(size_t)(c * 64 + l) * CONV_DIM + h * 64 + p4];
    float dt = dts[l];
    xv.x *= dt; xv.y *= dt; xv.z *= dt; xv.w *= dt;
    *(float4*)&Xs[l][p4] = xv;
  }
  __syncthreads();   // Xs, decay, ac, Bs, Cs all ready

  // ---- states[p][n] = sum_l Xs[l][p] * decay[l] * Bs[l][n] ----
  {
    int n = (tid & 63) * 2;           // lane-consecutive float2 over n
    int pg = (tid >> 6) * 16;         // wave-band over p
    float2 acc[16];
    #pragma unroll
    for (int k = 0; k < 16; k++) { acc[k].x = 0.f; acc[k].y = 0.f; }
    for (int l = 0; l < 64; l++) {
      float2 b2 = *(const float2*)&Bs[l][n];
      float dl = decay[l];
      b2.x *= dl; b2.y *= dl;
      #pragma unroll
      for (int k4 = 0; k4 < 4; k4++) {
        float4 xv = *(const float4*)&Xs[l][pg + k4 * 4];
        acc[k4 * 4 + 0].x += xv.x * b2.x; acc[k4 * 4 + 0].y += xv.x * b2.y;
        acc[k4 * 4 + 1].x += xv.y * b2.x; acc[k4 * 4 + 1].y += xv.y * b2.y;
        acc[k4 * 4 + 2].x += xv.z * b2.x; acc[k4 * 4 + 2].y += xv.z * b2.y;
        acc[k4 * 4 + 3].x += xv.w * b2.x; acc[k4 * 4 + 3].y += xv.w * b2.y;
      }
    }
    size_t sb = ((size_t)(h * NCHUNK + c) * 64 + pg) * 128 + n;
    #pragma unroll
    for (int k = 0; k < 16; k++)
      *(float2*)&states[sb + (size_t)k * 128] = acc[k];
  }

  // ---- G[i][j] = (C_i . B_j) * exp(ac_i - ac_j), j<=i else 0 ----
  {
    int i = tid & 63;                 // lane-consecutive rows of Cs
    int jb = (tid >> 6) * 16;         // wave-band over j
    float acc[16];
    #pragma unroll
    for (int jj = 0; jj < 16; jj++) acc[jj] = 0.f;
    for (int n4 = 0; n4 < 128; n4 += 4) {
      float4 cv = *(const float4*)&Cs[i][n4];
      #pragma unroll
      for (int jj = 0; jj < 16; jj++) {
        float4 bv = *(const float4*)&Bs[jb + jj][n4];   // broadcast
        acc[jj] += cv.x * bv.x + cv.y * bv.y + cv.z * bv.z + cv.w * bv.w;
      }
    }
    float aci = ac[i];
    #pragma unroll
    for (int q = 0; q < 4; q++) {
      float4 g;
      float* gp = &g.x;
      #pragma unroll
      for (int s = 0; s < 4; s++) {
        int j = jb + q * 4 + s;
        gp[s] = (j <= i) ? acc[q * 4 + s] * expf(aci - ac[j]) : 0.f;
      }
      *(float4*)&Gs[i][jb + q * 4] = g;
    }
  }
  __syncthreads();   // Gs ready; all Cs reads done

  // ---- Y[i][p] = sum_{j<=i} G[i][j] * Xs[j][p]  (banded i per wave) ----
  {
    int i = (tid >> 6) * 16 + (lane & 15);
    int pb = (lane >> 4) * 16;
    float acc[16];
    #pragma unroll
    for (int pp = 0; pp < 16; pp++) acc[pp] = 0.f;
    int jmax = i >> 2;
    for (int j4 = 0; j4 <= jmax; j4++) {
      float4 gv = *(const float4*)&Gs[i][j4 * 4];
      float* gp = &gv.x;
      #pragma unroll
      for (int q = 0; q < 4; q++) {
        float g = gp[q];
        #pragma unroll
        for (int pp4 = 0; pp4 < 4; pp4++) {
          float4 xv = *(const float4*)&Xs[j4 * 4 + q][pb + pp4 * 4];
          acc[pp4 * 4 + 0] += g * xv.x;
          acc[pp4 * 4 + 1] += g * xv.y;
          acc[pp4 * 4 + 2] += g * xv.z;
          acc[pp4 * 4 + 3] += g * xv.w;
        }
      }
    }
    // stage to Yt (reuses Cs space, stride 132)
    float* Yt = &Cs[0][0];
    #pragma unroll
    for (int pp4 = 0; pp4 < 4; pp4++) {
      float4 yv = make_float4(acc[pp4 * 4 + 0], acc[pp4 * 4 + 1],
                              acc[pp4 * 4 + 2], acc[pp4 * 4 + 3]);
      *(float4*)&Yt[i * 132 + pb + pp4 * 4] = yv;
    }
  }
  __syncthreads();
  // coalesced write-out
  {
    const float* Yt = &Cs[0][0];
    for (int idx = tid; idx < 64 * 16; idx += 256) {
      int l = idx >> 4, p4 = (idx & 15) << 2;
      float4 yv = *(const float4*)&Yt[l * 132 + p4];
      *(float4*)&ybuf[(size_t)(c * 64 + l) * D_INNER + h * 64 + p4] = yv;
    }
  }
}

// ---------------- SSD phase 2: inter-chunk scan (widened grid) ----------------
__global__ void ssd_scan_k(const float* __restrict__ states, const float* __restrict__ acum_g,
                           float* __restrict__ sprefix) {
  int h = blockIdx.x, seg = blockIdx.y;
  int e = seg * 1024 + threadIdx.x * 4;
  float4 S = make_float4(0.f, 0.f, 0.f, 0.f);
  for (int c = 0; c < NCHUNK; c++) {
    size_t off = (size_t)(h * NCHUNK + c) * 8192 + e;
    float d = expf(acum_g[(h * NCHUNK + c) * 64 + 63]);
    float4 v = *(const float4*)&states[off];
    *(float4*)&sprefix[off] = S;
    S.x = d * S.x + v.x;
    S.y = d * S.y + v.y;
    S.z = d * S.z + v.z;
    S.w = d * S.w + v.w;
  }
}

// ---------------- SSD phase 3 (register-tiled, float4-vectorized) ----------------
// Y[l][p] += exp(ac[l]) * sum_n C[l][n]*Sp[p][n] + x*D
__global__ __launch_bounds__(256) void ssd_phase3_k(
    const float* __restrict__ xbc, const float* __restrict__ sprefix,
    const float* __restrict__ acum_g, const float* __restrict__ Dv,
    float* __restrict__ ybuf) {
  __shared__ float Cs[64][132];
  __shared__ float Sp[64][128];
  __shared__ float ac[64];
  int c = blockIdx.x, h = blockIdx.y, tid = threadIdx.x;
  if (tid < 64) ac[tid] = acum_g[(h * NCHUNK + c) * 64 + tid];
  for (int idx = tid; idx < 64 * 32; idx += 256) {
    int r = idx >> 5, n4 = (idx & 31) << 2;
    *(float4*)&Cs[r][n4] =
        *(const float4*)&xbc[(size_t)(c * 64 + r) * CONV_DIM + D_INNER + D_STATE + n4];
    *(float4*)&Sp[r][n4] =
        *(const float4*)&sprefix[((size_t)(h * NCHUNK + c) * 64 + r) * 128 + n4];
  }
  __syncthreads();

  int l = tid & 63, pb = (tid >> 6) * 16;
  float acc[16];
  #pragma unroll
  for (int pp = 0; pp < 16; pp++) acc[pp] = 0.f;
  for (int n4 = 0; n4 < 128; n4 += 4) {
    float4 cv = *(const float4*)&Cs[l][n4];
    #pragma unroll
    for (int pp = 0; pp < 16; pp++) {
      float4 sv = *(const float4*)&Sp[pb + pp][n4];   // broadcast
      acc[pp] += cv.x * sv.x + cv.y * sv.y + cv.z * sv.z + cv.w * sv.w;
    }
  }
  float eal = expf(ac[l]);
  __syncthreads();          // all Cs/Sp reads done
  float* Yt = &Cs[0][0];    // reuse, stride 132
  #pragma unroll
  for (int pp4 = 0; pp4 < 4; pp4++) {
    float4 yv = make_float4(eal * acc[pp4 * 4 + 0], eal * acc[pp4 * 4 + 1],
                            eal * acc[pp4 * 4 + 2], eal * acc[pp4 * 4 + 3]);
    *(float4*)&Yt[l * 132 + pb + pp4 * 4] = yv;
  }
  __syncthreads();
  float Dh = Dv[h];
  for (int idx = tid; idx < 64 * 16; idx += 256) {
    int r = idx >> 4, p4 = (idx & 15) << 2;
    size_t yi = (size_t)(c * 64 + r) * D_INNER + h * 64 + p4;
    float4 y = *(const float4*)&ybuf[yi];
    float4 t = *(const float4*)&Yt[r * 132 + p4];
    float4 xv = *(const float4*)&xbc[(size_t)(c * 64 + r) * CONV_DIM + h * 64 + p4];
    y.x += t.x + xv.x * Dh;
    y.y += t.y + xv.y * Dh;
    y.z += t.z + xv.z * Dh;
    y.w += t.w + xv.w * Dh;
    *(float4*)&ybuf[yi] = y;
  }
}

// ---------------- host launch ----------------
extern "C" void kernel_launch(void* const* d_in, const int* in_sizes, int n_in,
                              void* d_out, int out_size, void* d_ws, size_t ws_size,
                              hipStream_t stream) {
  const int*   ids  = (const int*)d_in[0];
  const float* emb  = (const float*)d_in[1];
  const float* ipw  = (const float*)d_in[2];   // (4, 3352, 768)
  const float* cw   = (const float*)d_in[3];   // (4, 1792, 4)
  const float* cb   = (const float*)d_in[4];   // (4, 1792)
  const float* dtb  = (const float*)d_in[5];   // (4, 24)
  const float* alog = (const float*)d_in[6];   // (4, 24)
  const float* Dv   = (const float*)d_in[7];   // (4, 24)
  const float* mnw  = (const float*)d_in[8];   // (4, 1536)
  const float* opw  = (const float*)d_in[9];   // (4, 768, 1536)
  const float* lnw  = (const float*)d_in[10];  // (4, 768)
  const float* nfw  = (const float*)d_in[11];  // (768,)
  float* out = (float*)d_out;

  const size_t F_X   = (size_t)SEQLEN * D_MODEL;
  const size_t F_UHL = F_X / 2;
  const size_t F_EMB = (size_t)VOCAB * D_MODEL / 2;
  const size_t NEED_A = (F_X * 2 + F_UHL * 2 + F_EMB * 2) * sizeof(float);

  const size_t BIG_F = (size_t)SEQLEN * D_IN_PROJ + (size_t)SEQLEN * CONV_DIM +
                       (size_t)SEQLEN * NHEADS + (size_t)SEQLEN * D_INNER +
                       2ull * NHEADS * NCHUNK * CHUNK * D_STATE +
                       (size_t)NHEADS * NCHUNK * CHUNK;

  float* x = (float*)d_ws;
  float* u = x + F_X;

  bool pathA = ws_size >= NEED_A;

  if (pathA) {
    short* uh    = (short*)(u + F_X);
    short* ul    = uh + F_X;
    short* emb_h = (short*)((float*)d_ws + 2 * F_X + 2 * F_UHL);
    short* emb_l = emb_h + (size_t)VOCAB * D_MODEL;

    float* sb = (float*)d_out;
    short* gh   = (short*)sb;
    short* gl   = gh + (size_t)SEQLEN * D_INNER;
    short* ipwh = gl + (size_t)SEQLEN * D_INNER;
    short* ipwl = ipwh + (size_t)N_LAYER * D_IN_PROJ * D_MODEL;
    short* opwh = ipwl + (size_t)N_LAYER * D_IN_PROJ * D_MODEL;
    short* opwl = opwh + (size_t)N_LAYER * D_MODEL * D_INNER;
    float* big  = (float*)(opwl + (size_t)N_LAYER * D_MODEL * D_INNER);
    float* zx      = big;
    float* xbc     = zx + (size_t)SEQLEN * D_IN_PROJ;
    float* dtbuf   = xbc + (size_t)SEQLEN * CONV_DIM;
    float* ybuf    = dtbuf + (size_t)SEQLEN * NHEADS;
    float* states  = ybuf + (size_t)SEQLEN * D_INNER;
    float* sprefix = states + (size_t)NHEADS * NCHUNK * CHUNK * D_STATE;
    float* acum    = sprefix + (size_t)NHEADS * NCHUNK * CHUNK * D_STATE;

    split_k<<<4096, 256, 0, stream>>>(emb, emb_h, emb_l, (long)VOCAB * D_MODEL / 4);
    split_k<<<2048, 256, 0, stream>>>(ipw, ipwh, ipwl, (long)N_LAYER * D_IN_PROJ * D_MODEL / 4);
    split_k<<<1024, 256, 0, stream>>>(opw, opwh, opwl, (long)N_LAYER * D_MODEL * D_INNER / 4);

    embed_k<<<SEQLEN, 256, 0, stream>>>(ids, emb, x);

    for (int i = 0; i < N_LAYER; i++) {
      rmsnorm768_k<<<SEQLEN, 256, 0, stream>>>(x, lnw + i * D_MODEL, u, uh, ul);
      gemm_nt_hl_k<<<dim3(SEQLEN / GBM, (D_IN_PROJ + GBN - 1) / GBN), 256, 0, stream>>>(
          uh, ul, ipwh + (size_t)i * D_IN_PROJ * D_MODEL, ipwl + (size_t)i * D_IN_PROJ * D_MODEL,
          zx, nullptr, SEQLEN, D_IN_PROJ, D_MODEL);
      conv_dt_k<<<(SEQLEN * CONV_DIM) / 256, 256, 0, stream>>>(
          zx, cw + (size_t)i * CONV_DIM * D_CONV, cb + (size_t)i * CONV_DIM,
          dtb + i * NHEADS, xbc, dtbuf);
      ssd_phase1_k<<<dim3(NCHUNK, NHEADS), 256, 0, stream>>>(
          xbc, dtbuf, alog + i * NHEADS, ybuf, states, acum);
      ssd_scan_k<<<dim3(NHEADS, 8), 256, 0, stream>>>(states, acum, sprefix);
      ssd_phase3_k<<<dim3(NCHUNK, NHEADS), 256, 0, stream>>>(
          xbc, sprefix, acum, Dv + i * NHEADS, ybuf);
      gated_rmsnorm_k<<<SEQLEN, 256, 0, stream>>>(ybuf, zx, mnw + i * D_INNER, xbc, gh, gl);
      gemm_nt_hl_k<<<dim3(SEQLEN / GBM, D_MODEL / GBN), 256, 0, stream>>>(
          gh, gl, opwh + (size_t)i * D_MODEL * D_INNER, opwl + (size_t)i * D_MODEL * D_INNER,
          x, x, SEQLEN, D_MODEL, D_INNER);
    }

    rmsnorm768_k<<<SEQLEN, 256, 0, stream>>>(x, nfw, u, uh, ul);
    gemm_nt_hl_k<<<dim3(SEQLEN / GBM, (VOCAB + GBN - 1) / GBN), 256, 0, stream>>>(
        uh, ul, emb_h, emb_l, out, nullptr, SEQLEN, VOCAB, D_MODEL);
    return;
  }

  // ================= path B: fallback (convert-in-kernel) =================
  const size_t SMALL_F = 2ull * F_X;
  float* big = (ws_size >= (SMALL_F + BIG_F) * sizeof(float))
                   ? (u + F_X)
                   : (float*)d_out;
  float* zx      = big;
  float* xbc     = zx + (size_t)SEQLEN * D_IN_PROJ;
  float* dtbuf   = xbc + (size_t)SEQLEN * CONV_DIM;
  float* ybuf    = dtbuf + (size_t)SEQLEN * NHEADS;
  float* states  = ybuf + (size_t)SEQLEN * D_INNER;
  float* sprefix = states + (size_t)NHEADS * NCHUNK * CHUNK * D_STATE;
  float* acum    = sprefix + (size_t)NHEADS * NCHUNK * CHUNK * D_STATE;

  embed_k<<<SEQLEN, 256, 0, stream>>>(ids, emb, x);

  for (int i = 0; i < N_LAYER; i++) {
    rmsnorm768_k<<<SEQLEN, 256, 0, stream>>>(x, lnw + i * D_MODEL, u, nullptr, nullptr);
    gemm_nt_mfma_k<<<dim3(SEQLEN / GBM, (D_IN_PROJ + GBN - 1) / GBN), 256, 0, stream>>>(
        u, ipw + (size_t)i * D_IN_PROJ * D_MODEL, zx, nullptr, SEQLEN, D_IN_PROJ, D_MODEL);
    conv_dt_k<<<(SEQLEN * CONV_DIM) / 256, 256, 0, stream>>>(
        zx, cw + (size_t)i * CONV_DIM * D_CONV, cb + (size_t)i * CONV_DIM,
        dtb + i * NHEADS, xbc, dtbuf);
    ssd_phase1_k<<<dim3(NCHUNK, NHEADS), 256, 0, stream>>>(
        xbc, dtbuf, alog + i * NHEADS, ybuf, states, acum);
    ssd_scan_k<<<dim3(NHEADS, 8), 256, 0, stream>>>(states, acum, sprefix);
    ssd_phase3_k<<<dim3(NCHUNK, NHEADS), 256, 0, stream>>>(
        xbc, sprefix, acum, Dv + i * NHEADS, ybuf);
    gated_rmsnorm_k<<<SEQLEN, 256, 0, stream>>>(ybuf, zx, mnw + i * D_INNER, xbc, nullptr, nullptr);
    gemm_nt_mfma_k<<<dim3(SEQLEN / GBM, D_MODEL / GBN), 256, 0, stream>>>(
        xbc, opw + (size_t)i * D_MODEL * D_INNER, x, x, SEQLEN, D_MODEL, D_INNER);
  }

  rmsnorm768_k<<<SEQLEN, 256, 0, stream>>>(x, nfw, u, nullptr, nullptr);
  gemm_nt_mfma_k<<<dim3(SEQLEN / GBM, (VOCAB + GBN - 1) / GBN), 256, 0, stream>>>(
      u, emb, out, nullptr, SEQLEN, VOCAB, D_MODEL);
}